// Round 4
// baseline (24357.405 us; speedup 1.0000x reference)
//
#include <hip/hip_runtime.h>
#include <stdint.h>
#include <stddef.h>

// Problem constants (ESN_58317065945127)
#define B_    128
#define T_    2048
#define D_    128
#define H_    1024
#define O_    32
#define LAST_ 20

// Partition: 8 batch-blocks x 16 col-blocks = 128 WGs of 256 threads.
// Each WAVE owns a [16 batch x 16 col] tile and acts independently:
// no __syncthreads anywhere in the recurrence loop. Per-wave flags (64 per
// cohort) gate the steps; the flag-poll lock-steps a cohort to within one
// step, so RING_=4 has 2 slots of margin against overwrite.
#define NB_   8
#define NC_   16
#define RING_ 4

typedef __bf16 bf16x8 __attribute__((ext_vector_type(8)));
typedef __bf16 bf16x4 __attribute__((ext_vector_type(4)));
typedef float  f32x4  __attribute__((ext_vector_type(4)));

union Pack8  { unsigned long long u;    bf16x4 v; };
union Pack16 { unsigned long long u[2]; bf16x8 v; };

__device__ __forceinline__ float tanh_fast(float s) {
    float a = fminf(fmaxf(s, -12.0f), 12.0f);
    float e = __expf(2.0f * a);
    return (e - 1.0f) / (e + 1.0f);
}

// All cross-WG traffic via relaxed AGENT-scope atomics -> individual sc0/sc1
// loads/stores straight to the device coherence point. No __threadfence
// anywhere (R1 lesson: agent fences emit L2-wide wbl2/inv, ~22 us/step).
// Release = publish store -> s_waitcnt vmcnt(0) (LLC ack) -> flag store
// (R2-proven correct over 50 graph replays).
//
// Transposed compute: h_new^T = w_r^T @ h^T (weights = reg-resident A-frags).
//   C/D: col(ln&15)=batch, row(q*4+reg)=4 consecutive h columns -> 8B publish.
__global__ __launch_bounds__(256, 1) void esn_persist(
    const float* __restrict__ x, const float* __restrict__ w_in,
    const float* __restrict__ w_r, __bf16* __restrict__ h_ex,
    float* __restrict__ hs, int* __restrict__ flags)
{
    const int wg  = (int)blockIdx.x;
    const int bb  = wg & (NB_ - 1);  // cohort id; &7 co-lands cohort on one XCD (perf only)
    const int cb  = wg >> 3;
    const int tid = (int)threadIdx.x;
    const int wv  = tid >> 6;
    const int ln  = tid & 63;
    const int nn  = ln & 15;   // batch index within tile
    const int q   = ln >> 4;   // quad
    const int b0  = bb * 16;
    const int n0  = cb * 64 + wv * 16;

    // ---- one-time: weight fragments into registers (A-operand layout) ----
    bf16x8 win[4];                       // w_in cols, K=128 -> 4 chunks
    #pragma unroll
    for (int c = 0; c < 4; ++c) {
        bf16x8 f;
        #pragma unroll
        for (int j = 0; j < 8; ++j)
            f[j] = (__bf16)w_in[(size_t)(c * 32 + q * 8 + j) * H_ + (n0 + nn)];
        win[c] = f;
    }
    bf16x8 wr[32];                       // w_r cols, K=1024 -> 32 chunks (128 VGPR)
    #pragma unroll
    for (int kc = 0; kc < 32; ++kc) {
        bf16x8 f;
        #pragma unroll
        for (int j = 0; j < 8; ++j)
            f[j] = (__bf16)w_r[(size_t)(kc * 32 + q * 8 + j) * H_ + (n0 + nn)];
        wr[kc] = f;
    }

    // Spin deadline ~3s, checked every 1024 spins (off the fast path).
    // Only fires on a sync bug; guarantees the kernel returns.
    const unsigned long long tdead =
        __builtin_amdgcn_s_memrealtime() + 300000000ull;

    int* cfl    = flags + bb * 64;            // the 64 wave-flags of my cohort
    int* myflag = cfl + (cb * 4 + wv);
    const float* xrow = x + (size_t)(b0 + nn) * T_ * D_ + q * 8;  // x[b][t][k]
    const size_t hrow = (size_t)(b0 + nn) * H_;

    // x prefetch (distance 1): xn = fp32 for step t+1, xf = bf16 frags for t
    f32x4 xn[8];
    bf16x8 xf[4];
    {
        #pragma unroll
        for (int c = 0; c < 4; ++c) {
            xn[2 * c]     = *(const f32x4*)(xrow + c * 32);
            xn[2 * c + 1] = *(const f32x4*)(xrow + c * 32 + 4);
        }
        #pragma unroll
        for (int c = 0; c < 4; ++c) {
            bf16x8 f;
            #pragma unroll
            for (int j = 0; j < 4; ++j) {
                f[j]     = (__bf16)xn[2 * c][j];
                f[j + 4] = (__bf16)xn[2 * c + 1][j];
            }
            xf[c] = f;
        }
    }

    float hm0 = 0.f, hm1 = 0.f, hm2 = 0.f, hm3 = 0.f;  // fp32 master h

    for (int t = 0; t < T_; ++t) {
        // issue x loads for t+1 NOW (fly during poll + compute)
        {
            const int tn = (t + 1 < T_) ? t + 1 : T_ - 1;
            const float* xp = xrow + (size_t)tn * D_;
            #pragma unroll
            for (int c = 0; c < 4; ++c) {
                xn[2 * c]     = *(const f32x4*)(xp + c * 32);
                xn[2 * c + 1] = *(const f32x4*)(xp + c * 32 + 4);
            }
        }

        f32x4 acc0 = {0.f, 0.f, 0.f, 0.f};
        f32x4 acc1 = {0.f, 0.f, 0.f, 0.f};

        if (t > 0) {
            // ---- poll: all 64 lanes watch the cohort's 64 wave-flags ----
            const int want = t - 1;
            int spins = 0;
            for (;;) {
                int f = __hip_atomic_load(cfl + ln, __ATOMIC_RELAXED,
                                          __HIP_MEMORY_SCOPE_AGENT);
                if (__all(f >= want)) break;
                if (((++spins) & 1023) == 0 &&
                    __builtin_amdgcn_s_memrealtime() > tdead) break;  // anti-hang
            }

            // ---- batch-issue all 64 coherent u64 h-loads into af[32] ----
            // (compiler-managed waits; no manual vmcnt counting anywhere)
            const __bf16* hp = h_ex
                + (size_t)((t - 1) & (RING_ - 1)) * (B_ * H_) + hrow + q * 8;
            bf16x8 af[32];
            #pragma unroll
            for (int kc = 0; kc < 32; ++kc) {
                Pack16 pk;
                pk.u[0] = __hip_atomic_load(
                    (const unsigned long long*)(hp + kc * 32),
                    __ATOMIC_RELAXED, __HIP_MEMORY_SCOPE_AGENT);
                pk.u[1] = __hip_atomic_load(
                    (const unsigned long long*)(hp + kc * 32 + 4),
                    __ATOMIC_RELAXED, __HIP_MEMORY_SCOPE_AGENT);
                af[kc] = pk.v;
            }

            // x-projection MFMAs fill part of the load latency
            #pragma unroll
            for (int c = 0; c < 4; ++c)
                acc0 = __builtin_amdgcn_mfma_f32_16x16x32_bf16(win[c], xf[c], acc0, 0, 0, 0);

            // recurrent MFMAs; two acc chains break the dependency depth
            #pragma unroll
            for (int kc = 0; kc < 32; ++kc) {
                if (kc & 1) acc1 = __builtin_amdgcn_mfma_f32_16x16x32_bf16(wr[kc], af[kc], acc1, 0, 0, 0);
                else        acc0 = __builtin_amdgcn_mfma_f32_16x16x32_bf16(wr[kc], af[kc], acc0, 0, 0, 0);
            }
        } else {
            #pragma unroll
            for (int c = 0; c < 4; ++c)
                acc0 = __builtin_amdgcn_mfma_f32_16x16x32_bf16(win[c], xf[c], acc0, 0, 0, 0);
        }

        const f32x4 acc = acc0 + acc1;
        const float th0 = tanh_fast(acc[0]);
        const float th1 = tanh_fast(acc[1]);
        const float th2 = tanh_fast(acc[2]);
        const float th3 = tanh_fast(acc[3]);
        if (t == 0) {           // reference: h = tanh(xw[:,0]), no leak at t=0
            hm0 = th0; hm1 = th1; hm2 = th2; hm3 = th3;
        } else {                // h = 0.1*h + 0.9*tanh(.)
            hm0 = 0.1f * hm0 + 0.9f * th0;
            hm1 = 0.1f * hm1 + 0.9f * th1;
            hm2 = 0.1f * hm2 + 0.9f * th2;
            hm3 = 0.1f * hm3 + 0.9f * th3;
        }

        // publish 8B packed slice -> vmcnt(0) (LLC ack) -> per-wave flag
        {
            Pack8 p;
            p.v = (bf16x4){(__bf16)hm0, (__bf16)hm1, (__bf16)hm2, (__bf16)hm3};
            unsigned long long* op = (unsigned long long*)
                (h_ex + (size_t)(t & (RING_ - 1)) * (B_ * H_) + hrow + n0 + q * 4);
            __hip_atomic_store(op, p.u, __ATOMIC_RELAXED,
                               __HIP_MEMORY_SCOPE_AGENT);
        }
        asm volatile("s_waitcnt vmcnt(0)" ::: "memory");
        if (ln == 0)
            __hip_atomic_store(myflag, t, __ATOMIC_RELAXED,
                               __HIP_MEMORY_SCOPE_AGENT);

        // off the critical path: tail collection + x bf16 conversion for t+1
        if (t >= T_ - LAST_) {
            f32x4* sp = (f32x4*)(hs + (size_t)(t - (T_ - LAST_)) * (B_ * H_)
                                    + hrow + n0 + q * 4);
            *sp = (f32x4){hm0, hm1, hm2, hm3};
        }
        #pragma unroll
        for (int c = 0; c < 4; ++c) {
            bf16x8 f;
            #pragma unroll
            for (int j = 0; j < 4; ++j) {
                f[j]     = (__bf16)xn[2 * c][j];
                f[j + 4] = (__bf16)xn[2 * c + 1][j];
            }
            xf[c] = f;
        }
    }
}

// Readout: out[b,:] = cat(hs)[b,:] @ W + bias.  One block per batch row.
__global__ __launch_bounds__(256) void esn_out(
    const float* __restrict__ hs, const float* __restrict__ Wm,
    const float* __restrict__ bias, float* __restrict__ out)
{
    const int b   = (int)blockIdx.x;
    const int tid = (int)threadIdx.x;
    float acc[O_];
    #pragma unroll
    for (int o = 0; o < O_; ++o) acc[o] = 0.f;

    for (int k = tid; k < LAST_ * H_; k += 256) {
        // cat order: k = t'*H + c  <->  hs[t'][b][c]
        const float hv = hs[(size_t)(k >> 10) * (B_ * H_) + (size_t)b * H_ + (k & (H_ - 1))];
        const f32x4* wp = (const f32x4*)(Wm + (size_t)k * O_);
        #pragma unroll
        for (int v = 0; v < 8; ++v) {
            f32x4 w4 = wp[v];
            acc[4 * v + 0] = fmaf(hv, w4[0], acc[4 * v + 0]);
            acc[4 * v + 1] = fmaf(hv, w4[1], acc[4 * v + 1]);
            acc[4 * v + 2] = fmaf(hv, w4[2], acc[4 * v + 2]);
            acc[4 * v + 3] = fmaf(hv, w4[3], acc[4 * v + 3]);
        }
    }

    __shared__ float red[256][O_ + 1];  // +1 pad: conflict-free column sums
    #pragma unroll
    for (int o = 0; o < O_; ++o) red[tid][o] = acc[o];
    __syncthreads();
    if (tid < O_) {
        float s = bias[tid];
        for (int i = 0; i < 256; ++i) s += red[i][tid];
        out[(size_t)b * O_ + tid] = s;
    }
}

extern "C" void kernel_launch(void* const* d_in, const int* in_sizes, int n_in,
                              void* d_out, int out_size, void* d_ws, size_t ws_size,
                              hipStream_t stream)
{
    const float* x    = (const float*)d_in[0];  // [128,2048,128]
    const float* w_in = (const float*)d_in[1];  // [128,1024]
    const float* w_r  = (const float*)d_in[2];  // [1024,1024]
    const float* Wm   = (const float*)d_in[3];  // [20480,32]
    const float* bias = (const float*)d_in[4];  // [32]
    float* out        = (float*)d_out;          // [128,32]

    const size_t flag_bytes = 4096;                                      // 512 ints used
    const size_t hex_bytes  = (size_t)RING_ * B_ * H_ * sizeof(__bf16);  // 1 MiB
    const size_t hs_bytes   = (size_t)LAST_ * B_ * H_ * sizeof(float);   // 10 MiB
    if (ws_size < flag_bytes + hex_bytes + hs_bytes) return;  // fail loud, not corrupt

    int*    flags = (int*)d_ws;
    __bf16* h_ex  = (__bf16*)((char*)d_ws + flag_bytes);
    float*  hs    = (float*)((char*)d_ws + flag_bytes + hex_bytes);

    // flags = -1 ("nothing published"); ws is re-poisoned 0xAA before every call
    hipMemsetAsync(flags, 0xFF, flag_bytes, stream);

    hipLaunchKernelGGL(esn_persist, dim3(NB_ * NC_), dim3(256), 0, stream,
                       x, w_in, w_r, h_ex, hs, flags);
    hipLaunchKernelGGL(esn_out, dim3(B_), dim3(256), 0, stream,
                       hs, Wm, bias, out);
}

// Round 5
// 10072.012 us; speedup vs baseline: 2.4183x; 2.4183x over previous
//
#include <hip/hip_runtime.h>
#include <stdint.h>
#include <stddef.h>

// Problem constants (ESN_58317065945127)
#define B_    128
#define T_    2048
#define D_    128
#define H_    1024
#define O_    32
#define LAST_ 20

// Partition: 8 batch-blocks x 16 col-blocks = 128 WGs of 256 threads.
// Per-wave flags (64/cohort) gate steps; flag-gating bounds wave drift to
// <=2 steps, so RING_=4 is safe (writer at t+2 vs reader of t-1: slots differ).
#define NB_   8
#define NC_   16
#define RING_ 4

typedef __bf16 bf16x8 __attribute__((ext_vector_type(8)));
typedef __bf16 bf16x4 __attribute__((ext_vector_type(4)));
typedef float  f32x4  __attribute__((ext_vector_type(4)));

union Pack8  { unsigned long long u;    bf16x4 v; };
union Pack16 { unsigned long long u[2]; bf16x8 v; };

__device__ __forceinline__ float tanh_fast(float s) {
    float a = fminf(fmaxf(s, -12.0f), 12.0f);
    float e = __expf(2.0f * a);
    return (e - 1.0f) / (e + 1.0f);
}

// Cross-WG traffic via relaxed AGENT-scope atomics (individual sc0/sc1 ops,
// no cache-wide wbl2/inv — R1 lesson). Release = publish -> vmcnt(0) -> flag.
//
// R5: LDS-staged h exchange. Each wave coherently loads a DISTINCT 8KB
// quarter of the WG's h(t-1) block (16 batched u64 loads), ds_writes into a
// double-buffered 64KB LDS tile, one __syncthreads, then MFMA fragments come
// from ds_read_b128 (compiler pipelines lgkmcnt well). 4x fewer coherent
// loads; global-load phase = 16 parallel issues + one LLC round-trip.
// XOR chunk swizzle (phys_ch = ch ^ (row&7)) de-conflicts the bank-aligned
// 2048B row stride for both writers and readers.
__global__ __launch_bounds__(256, 1) void esn_persist(
    const float* __restrict__ x, const float* __restrict__ w_in,
    const float* __restrict__ w_r, __bf16* __restrict__ h_ex,
    float* __restrict__ hs, int* __restrict__ flags)
{
    __shared__ bf16x8 ls[2][16][128];   // 2 bufs x 16 batch-rows x 128 16B chunks = 64 KiB

    const int wg  = (int)blockIdx.x;
    const int bb  = wg & (NB_ - 1);  // cohort id; &7 co-lands cohort on one XCD (perf only)
    const int cb  = wg >> 3;
    const int tid = (int)threadIdx.x;
    const int wv  = tid >> 6;
    const int ln  = tid & 63;
    const int nn  = ln & 15;   // batch index within tile
    const int q   = ln >> 4;   // quad
    const int b0  = bb * 16;
    const int n0  = cb * 64 + wv * 16;

    // ---- one-time: weight fragments into registers (A-operand layout) ----
    bf16x8 win[4];                       // w_in cols, K=128 -> 4 chunks
    #pragma unroll
    for (int c = 0; c < 4; ++c) {
        bf16x8 f;
        #pragma unroll
        for (int j = 0; j < 8; ++j)
            f[j] = (__bf16)w_in[(size_t)(c * 32 + q * 8 + j) * H_ + (n0 + nn)];
        win[c] = f;
    }
    bf16x8 wr[32];                       // w_r cols, K=1024 -> 32 chunks (128 regs)
    #pragma unroll
    for (int kc = 0; kc < 32; ++kc) {
        bf16x8 f;
        #pragma unroll
        for (int j = 0; j < 8; ++j)
            f[j] = (__bf16)w_r[(size_t)(kc * 32 + q * 8 + j) * H_ + (n0 + nn)];
        wr[kc] = f;
    }

    // Spin deadline ~3s, checked every 256 sleeps (off the fast path).
    const unsigned long long tdead =
        __builtin_amdgcn_s_memrealtime() + 300000000ull;

    int* cfl    = flags + bb * 64;            // the 64 wave-flags of my cohort
    int* myflag = cfl + (cb * 4 + wv);
    const float* xrow = x + (size_t)(b0 + nn) * T_ * D_ + q * 8;  // x[b][t][k]
    const size_t hrow = (size_t)(b0 + nn) * H_;

    // x prefetch (distance 1): xn = fp32 for step t+1, xf = bf16 frags for t
    f32x4 xn[8];
    bf16x8 xf[4];
    {
        #pragma unroll
        for (int c = 0; c < 4; ++c) {
            xn[2 * c]     = *(const f32x4*)(xrow + c * 32);
            xn[2 * c + 1] = *(const f32x4*)(xrow + c * 32 + 4);
        }
        #pragma unroll
        for (int c = 0; c < 4; ++c) {
            bf16x8 f;
            #pragma unroll
            for (int j = 0; j < 4; ++j) {
                f[j]     = (__bf16)xn[2 * c][j];
                f[j + 4] = (__bf16)xn[2 * c + 1][j];
            }
            xf[c] = f;
        }
    }

    float hm0 = 0.f, hm1 = 0.f, hm2 = 0.f, hm3 = 0.f;  // fp32 master h

    for (int t = 0; t < T_; ++t) {
        // issue x loads for t+1 NOW (fly during poll + compute)
        {
            const int tn = (t + 1 < T_) ? t + 1 : T_ - 1;
            const float* xp = xrow + (size_t)tn * D_;
            #pragma unroll
            for (int c = 0; c < 4; ++c) {
                xn[2 * c]     = *(const f32x4*)(xp + c * 32);
                xn[2 * c + 1] = *(const f32x4*)(xp + c * 32 + 4);
            }
        }

        f32x4 acc0 = {0.f, 0.f, 0.f, 0.f};
        f32x4 acc1 = {0.f, 0.f, 0.f, 0.f};

        if (t > 0) {
            // ---- poll cohort flags (all 64 lanes, with s_sleep backoff) ----
            const int want = t - 1;
            int spins = 0;
            for (;;) {
                int f = __hip_atomic_load(cfl + ln, __ATOMIC_RELAXED,
                                          __HIP_MEMORY_SCOPE_AGENT);
                if (__all(f >= want)) break;
                __builtin_amdgcn_s_sleep(1);      // ~64 cyc; cuts flag-line pressure
                if (((++spins) & 255) == 0 &&
                    __builtin_amdgcn_s_memrealtime() > tdead) break;  // anti-hang
            }

            // ---- stage h(t-1) into LDS: wave wv loads its 8KB quarter ----
            const int sb = (t - 1) & 1;
            const __bf16* hbase = h_ex
                + (size_t)((t - 1) & (RING_ - 1)) * (B_ * H_) + (size_t)b0 * H_;
            Pack16 pk[8];
            #pragma unroll
            for (int i = 0; i < 8; ++i) {
                const int p = wv * 512 + i * 64 + ln;   // 16B piece index
                const unsigned long long* gp = (const unsigned long long*)
                    (hbase + (size_t)(p >> 7) * H_ + (p & 127) * 8);
                pk[i].u[0] = __hip_atomic_load(gp, __ATOMIC_RELAXED,
                                               __HIP_MEMORY_SCOPE_AGENT);
                pk[i].u[1] = __hip_atomic_load(gp + 1, __ATOMIC_RELAXED,
                                               __HIP_MEMORY_SCOPE_AGENT);
            }
            asm volatile("" ::: "memory");  // keep all 16 issues ahead of the writes
            #pragma unroll
            for (int i = 0; i < 8; ++i) {
                const int p = wv * 512 + i * 64 + ln;
                const int r = p >> 7, ch = p & 127;
                ls[sb][r][ch ^ (r & 7)] = pk[i].v;   // XOR swizzle
            }

            // x-projection MFMAs before the barrier (independent of staging)
            #pragma unroll
            for (int c = 0; c < 4; ++c)
                acc0 = __builtin_amdgcn_mfma_f32_16x16x32_bf16(win[c], xf[c], acc0, 0, 0, 0);

            __syncthreads();

            // ---- recurrent MFMAs, fragments straight from LDS ----
            #pragma unroll
            for (int kc = 0; kc < 32; ++kc) {
                bf16x8 a = ls[sb][nn][(kc * 4 + q) ^ (nn & 7)];
                if (kc & 1) acc1 = __builtin_amdgcn_mfma_f32_16x16x32_bf16(wr[kc], a, acc1, 0, 0, 0);
                else        acc0 = __builtin_amdgcn_mfma_f32_16x16x32_bf16(wr[kc], a, acc0, 0, 0, 0);
            }
        } else {
            #pragma unroll
            for (int c = 0; c < 4; ++c)
                acc0 = __builtin_amdgcn_mfma_f32_16x16x32_bf16(win[c], xf[c], acc0, 0, 0, 0);
        }

        const f32x4 acc = acc0 + acc1;
        const float th0 = tanh_fast(acc[0]);
        const float th1 = tanh_fast(acc[1]);
        const float th2 = tanh_fast(acc[2]);
        const float th3 = tanh_fast(acc[3]);
        if (t == 0) {           // reference: h = tanh(xw[:,0]), no leak at t=0
            hm0 = th0; hm1 = th1; hm2 = th2; hm3 = th3;
        } else {                // h = 0.1*h + 0.9*tanh(.)
            hm0 = 0.1f * hm0 + 0.9f * th0;
            hm1 = 0.1f * hm1 + 0.9f * th1;
            hm2 = 0.1f * hm2 + 0.9f * th2;
            hm3 = 0.1f * hm3 + 0.9f * th3;
        }

        // publish 8B packed slice -> vmcnt(0) (LLC ack) -> per-wave flag
        {
            Pack8 p;
            p.v = (bf16x4){(__bf16)hm0, (__bf16)hm1, (__bf16)hm2, (__bf16)hm3};
            unsigned long long* op = (unsigned long long*)
                (h_ex + (size_t)(t & (RING_ - 1)) * (B_ * H_) + hrow + n0 + q * 4);
            __hip_atomic_store(op, p.u, __ATOMIC_RELAXED,
                               __HIP_MEMORY_SCOPE_AGENT);
        }
        asm volatile("s_waitcnt vmcnt(0)" ::: "memory");
        if (ln == 0)
            __hip_atomic_store(myflag, t, __ATOMIC_RELAXED,
                               __HIP_MEMORY_SCOPE_AGENT);

        // off the critical path: tail collection + x bf16 conversion for t+1
        if (t >= T_ - LAST_) {
            f32x4* sp = (f32x4*)(hs + (size_t)(t - (T_ - LAST_)) * (B_ * H_)
                                    + hrow + n0 + q * 4);
            *sp = (f32x4){hm0, hm1, hm2, hm3};
        }
        #pragma unroll
        for (int c = 0; c < 4; ++c) {
            bf16x8 f;
            #pragma unroll
            for (int j = 0; j < 4; ++j) {
                f[j]     = (__bf16)xn[2 * c][j];
                f[j + 4] = (__bf16)xn[2 * c + 1][j];
            }
            xf[c] = f;
        }
    }
}

// Readout: out[b,:] = cat(hs)[b,:] @ W + bias.  One block per batch row.
__global__ __launch_bounds__(256) void esn_out(
    const float* __restrict__ hs, const float* __restrict__ Wm,
    const float* __restrict__ bias, float* __restrict__ out)
{
    const int b   = (int)blockIdx.x;
    const int tid = (int)threadIdx.x;
    float acc[O_];
    #pragma unroll
    for (int o = 0; o < O_; ++o) acc[o] = 0.f;

    for (int k = tid; k < LAST_ * H_; k += 256) {
        // cat order: k = t'*H + c  <->  hs[t'][b][c]
        const float hv = hs[(size_t)(k >> 10) * (B_ * H_) + (size_t)b * H_ + (k & (H_ - 1))];
        const f32x4* wp = (const f32x4*)(Wm + (size_t)k * O_);
        #pragma unroll
        for (int v = 0; v < 8; ++v) {
            f32x4 w4 = wp[v];
            acc[4 * v + 0] = fmaf(hv, w4[0], acc[4 * v + 0]);
            acc[4 * v + 1] = fmaf(hv, w4[1], acc[4 * v + 1]);
            acc[4 * v + 2] = fmaf(hv, w4[2], acc[4 * v + 2]);
            acc[4 * v + 3] = fmaf(hv, w4[3], acc[4 * v + 3]);
        }
    }

    __shared__ float red[256][O_ + 1];  // +1 pad: conflict-free column sums
    #pragma unroll
    for (int o = 0; o < O_; ++o) red[tid][o] = acc[o];
    __syncthreads();
    if (tid < O_) {
        float s = bias[tid];
        for (int i = 0; i < 256; ++i) s += red[i][tid];
        out[(size_t)b * O_ + tid] = s;
    }
}

extern "C" void kernel_launch(void* const* d_in, const int* in_sizes, int n_in,
                              void* d_out, int out_size, void* d_ws, size_t ws_size,
                              hipStream_t stream)
{
    const float* x    = (const float*)d_in[0];  // [128,2048,128]
    const float* w_in = (const float*)d_in[1];  // [128,1024]
    const float* w_r  = (const float*)d_in[2];  // [1024,1024]
    const float* Wm   = (const float*)d_in[3];  // [20480,32]
    const float* bias = (const float*)d_in[4];  // [32]
    float* out        = (float*)d_out;          // [128,32]

    const size_t flag_bytes = 4096;                                      // 512 ints used
    const size_t hex_bytes  = (size_t)RING_ * B_ * H_ * sizeof(__bf16);  // 1 MiB
    const size_t hs_bytes   = (size_t)LAST_ * B_ * H_ * sizeof(float);   // 10 MiB
    if (ws_size < flag_bytes + hex_bytes + hs_bytes) return;  // fail loud, not corrupt

    int*    flags = (int*)d_ws;
    __bf16* h_ex  = (__bf16*)((char*)d_ws + flag_bytes);
    float*  hs    = (float*)((char*)d_ws + flag_bytes + hex_bytes);

    // flags = -1 ("nothing published"); ws is re-poisoned 0xAA before every call
    hipMemsetAsync(flags, 0xFF, flag_bytes, stream);

    hipLaunchKernelGGL(esn_persist, dim3(NB_ * NC_), dim3(256), 0, stream,
                       x, w_in, w_r, h_ex, hs, flags);
    hipLaunchKernelGGL(esn_out, dim3(B_), dim3(256), 0, stream,
                       hs, Wm, bias, out);
}